// Round 1
// baseline (1792.084 us; speedup 1.0000x reference)
//
#include <hip/hip_runtime.h>
#include <cstdint>
#include <cstddef>

#define NROWS 16384
#define DDIM  256
#define KCODES 8192

// ---------------------------------------------------------------------------
// K0: row squared norms for inputs (x2[N]) and embedding (e2[K]).
// One wave (64 lanes) per row; lane loads float4 (64*4 = 256 = DDIM).
// ---------------------------------------------------------------------------
__global__ void k_sqnorms(const float* __restrict__ inp, const float* __restrict__ emb,
                          float* __restrict__ x2, float* __restrict__ e2) {
  int wave = threadIdx.x >> 6, lane = threadIdx.x & 63;
  int row = blockIdx.x * 4 + wave;  // 0 .. NROWS+KCODES-1
  const float* src = (row < NROWS) ? (inp + (size_t)row * DDIM)
                                   : (emb + (size_t)(row - NROWS) * DDIM);
  float4 v = ((const float4*)src)[lane];
  float s = v.x * v.x + v.y * v.y + v.z * v.z + v.w * v.w;
#pragma unroll
  for (int o = 32; o >= 1; o >>= 1) s += __shfl_down(s, o, 64);
  if (lane == 0) {
    if (row < NROWS) x2[row] = s;
    else e2[row - NROWS] = s;
  }
}

// ---------------------------------------------------------------------------
// K1: fused distance GEMM + running row argmin.
// Block tile: 64 rows x 128 cols, 256 threads (16x16), thread tile 4x8.
// Each block scans 1/4 of the codebook (col-split 4 -> 1024 blocks, 4/CU-ish).
// d2 = (x2 + e2) - 2*dot, mirroring the reference's fp32 formula order.
// LDS stride padded +4 (36) to keep float4 stores aligned and reads <=2-way
// bank-aliased (free on CDNA4 per m136).
// ---------------------------------------------------------------------------
__global__ __launch_bounds__(256, 2) void k_argmin(
    const float* __restrict__ inp, const float* __restrict__ emb,
    const float* __restrict__ x2, const float* __restrict__ e2,
    float* __restrict__ pmin, int* __restrict__ pidx) {
  __shared__ float xs[64][36];
  __shared__ float es[128][36];
  const int tid = threadIdx.x;
  const int ty = tid >> 4, tx = tid & 15;
  const int rt = blockIdx.x & 255;   // row tile 0..255
  const int cs = blockIdx.x >> 8;    // col split 0..3
  const int row0 = rt * 64;

  float rmin[4];
  int ridx[4];
#pragma unroll
  for (int r = 0; r < 4; ++r) { rmin[r] = 3.4e38f; ridx[r] = 0x7fffffff; }
  float x2r[4];
#pragma unroll
  for (int r = 0; r < 4; ++r) x2r[r] = x2[row0 + ty * 4 + r];

  for (int t = 0; t < 16; ++t) {
    const int c0 = cs * 2048 + t * 128;
    float acc[4][8];
#pragma unroll
    for (int r = 0; r < 4; ++r)
#pragma unroll
      for (int c = 0; c < 8; ++c) acc[r][c] = 0.0f;

    for (int kb = 0; kb < DDIM; kb += 32) {
      __syncthreads();
#pragma unroll
      for (int i = 0; i < 2; ++i) {
        int q = i * 256 + tid, r = q >> 3, k4 = (q & 7) * 4;
        float4 v = *(const float4*)(inp + (size_t)(row0 + r) * DDIM + kb + k4);
        *(float4*)&xs[r][k4] = v;
      }
#pragma unroll
      for (int i = 0; i < 4; ++i) {
        int q = i * 256 + tid, r = q >> 3, k4 = (q & 7) * 4;
        float4 v = *(const float4*)(emb + (size_t)(c0 + r) * DDIM + kb + k4);
        *(float4*)&es[r][k4] = v;
      }
      __syncthreads();
#pragma unroll
      for (int kk = 0; kk < 32; ++kk) {
        float xv[4], ev[8];
#pragma unroll
        for (int r = 0; r < 4; ++r) xv[r] = xs[ty * 4 + r][kk];
#pragma unroll
        for (int c = 0; c < 8; ++c) ev[c] = es[c * 16 + tx][kk];
#pragma unroll
        for (int r = 0; r < 4; ++r)
#pragma unroll
          for (int c = 0; c < 8; ++c) acc[r][c] = fmaf(xv[r], ev[c], acc[r][c]);
      }
    }
    // epilogue: d2 + running argmin (cols ascend per-thread, strict < keeps first)
#pragma unroll
    for (int c = 0; c < 8; ++c) {
      int col = c0 + c * 16 + tx;
      float e2c = e2[col];
#pragma unroll
      for (int r = 0; r < 4; ++r) {
        float d2 = (x2r[r] + e2c) - 2.0f * acc[r][c];
        if (d2 < rmin[r] || (d2 == rmin[r] && col < ridx[r])) { rmin[r] = d2; ridx[r] = col; }
      }
    }
  }
  // reduce across the 16 tx lanes that share the same rows (xor stays in-group)
#pragma unroll
  for (int r = 0; r < 4; ++r) {
    float v = rmin[r];
    int id = ridx[r];
#pragma unroll
    for (int o = 1; o < 16; o <<= 1) {
      float v2 = __shfl_xor(v, o, 64);
      int i2 = __shfl_xor(id, o, 64);
      if (v2 < v || (v2 == v && i2 < id)) { v = v2; id = i2; }
    }
    if (tx == 0) {
      pmin[(size_t)(row0 + ty * 4 + r) * 4 + cs] = v;
      pidx[(size_t)(row0 + ty * 4 + r) * 4 + cs] = id;
    }
  }
}

// ---------------------------------------------------------------------------
// K1b: merge the 4 col-split partials per row -> final index (smaller idx wins ties)
// ---------------------------------------------------------------------------
__global__ void k_merge(const float* __restrict__ pmin, const int* __restrict__ pidx,
                        int* __restrict__ idxb) {
  int i = blockIdx.x * blockDim.x + threadIdx.x;
  if (i >= NROWS) return;
  float best = 3.4e38f;
  int bid = 0x7fffffff;
#pragma unroll
  for (int s = 0; s < 4; ++s) {
    float v = pmin[(size_t)i * 4 + s];
    int id = pidx[(size_t)i * 4 + s];
    if (v < best || (v == best && id < bid)) { best = v; bid = id; }
  }
  idxb[i] = bid;
}

// ---------------------------------------------------------------------------
// K2: per-row scatter: quantized (STE arithmetic), encodings one-hot,
// counts / dw (fp32 atomics), commitment-loss partial sums.
// One wave per row.
// ---------------------------------------------------------------------------
__global__ void k_scatter(const float* __restrict__ inp, const float* __restrict__ emb,
                          const int* __restrict__ idxb,
                          float* __restrict__ out_quant, float* __restrict__ out_enc,
                          float* __restrict__ counts, float* __restrict__ dw,
                          float* __restrict__ loss_acc) {
  __shared__ float wsum[4];
  int wave = threadIdx.x >> 6, lane = threadIdx.x & 63;
  int row = blockIdx.x * 4 + wave;
  int j = idxb[row];
  float4 x = *(const float4*)(inp + (size_t)row * DDIM + lane * 4);
  float4 e = *(const float4*)(emb + (size_t)j * DDIM + lane * 4);
  // quantized = inputs + (quantized_raw - inputs)   (mirror reference STE arithmetic)
  size_t qo = (size_t)row * DDIM + lane * 4;  // out_quant base is only 4B-aligned -> scalar stores
  out_quant[qo + 0] = x.x + (e.x - x.x);
  out_quant[qo + 1] = x.y + (e.y - x.y);
  out_quant[qo + 2] = x.z + (e.z - x.z);
  out_quant[qo + 3] = x.w + (e.w - x.w);
  size_t dwo = (size_t)j * DDIM + lane * 4;
  atomicAdd(&dw[dwo + 0], x.x);
  atomicAdd(&dw[dwo + 1], x.y);
  atomicAdd(&dw[dwo + 2], x.z);
  atomicAdd(&dw[dwo + 3], x.w);
  float d0 = e.x - x.x, d1 = e.y - x.y, d2 = e.z - x.z, d3 = e.w - x.w;
  float s = d0 * d0 + d1 * d1 + d2 * d2 + d3 * d3;
#pragma unroll
  for (int o = 32; o >= 1; o >>= 1) s += __shfl_down(s, o, 64);
  if (lane == 0) {
    atomicAdd(&counts[j], 1.0f);
    out_enc[(size_t)row * KCODES + j] = 1.0f;
    wsum[wave] = s;
  }
  __syncthreads();
  if (threadIdx.x == 0) atomicAdd(loss_acc, wsum[0] + wsum[1] + wsum[2] + wsum[3]);
}

// ---------------------------------------------------------------------------
// K3: single block: n = sum(ecs_raw), normalized ecs, perplexity, loss.
// ---------------------------------------------------------------------------
__global__ void k_stats(const float* __restrict__ counts, const float* __restrict__ ema_cs,
                        const float* __restrict__ loss_acc,
                        float* __restrict__ out_loss, float* __restrict__ out_perp,
                        float* __restrict__ out_ecs) {
  __shared__ float red[8];
  int tid = threadIdx.x;
  float ln = 0.0f, lp = 0.0f;
  for (int k = tid; k < KCODES; k += 256) {
    float c = counts[k];
    float er = ema_cs[k] * 0.99f + 0.01f * c;
    ln += er;
    float p = c * (1.0f / 16384.0f);
    lp += p * logf(p + 1e-10f);
  }
  int lane = tid & 63, wave = tid >> 6;
#pragma unroll
  for (int o = 32; o >= 1; o >>= 1) {
    ln += __shfl_down(ln, o, 64);
    lp += __shfl_down(lp, o, 64);
  }
  if (lane == 0) { red[wave] = ln; red[wave + 4] = lp; }
  __syncthreads();
  float n = red[0] + red[1] + red[2] + red[3];
  float plsum = red[4] + red[5] + red[6] + red[7];
  float denom = n + 0.08192f;  // n + K*EPSILON
  for (int k = tid; k < KCODES; k += 256) {
    float c = counts[k];
    float er = ema_cs[k] * 0.99f + 0.01f * c;
    out_ecs[k] = (er + 1e-5f) / denom * n;  // mirror reference op order
  }
  if (tid == 0) {
    out_loss[0] = 0.25f * (loss_acc[0] / 4194304.0f);  // /(N*D), exact pow2
    out_perp[0] = expf(-plsum);
  }
}

// ---------------------------------------------------------------------------
// K4: new_ema_w = ema_w*0.99 + 0.01*dw ; new_embedding = new_ema_w / ecs[k]
// Outputs are only 8B-aligned in d_out -> float2 stores.
// ---------------------------------------------------------------------------
__global__ void k_update(const float* __restrict__ ema_w, const float* __restrict__ dw,
                         const float* __restrict__ ecs,
                         float* __restrict__ out_emaw, float* __restrict__ out_emb) {
  size_t i = ((size_t)blockIdx.x * blockDim.x + threadIdx.x) * 4;
  int k = (int)(i >> 8);
  float4 w = *(const float4*)(ema_w + i);
  float4 d = *(const float4*)(dw + i);
  float ec = ecs[k];
  float nw0 = w.x * 0.99f + 0.01f * d.x;
  float nw1 = w.y * 0.99f + 0.01f * d.y;
  float nw2 = w.z * 0.99f + 0.01f * d.z;
  float nw3 = w.w * 0.99f + 0.01f * d.w;
  float2 a0 = make_float2(nw0, nw1), a1 = make_float2(nw2, nw3);
  float2 b0 = make_float2(nw0 / ec, nw1 / ec), b1 = make_float2(nw2 / ec, nw3 / ec);
  *(float2*)(out_emaw + i) = a0;
  *(float2*)(out_emaw + i + 2) = a1;
  *(float2*)(out_emb + i) = b0;
  *(float2*)(out_emb + i + 2) = b1;
}

extern "C" void kernel_launch(void* const* d_in, const int* in_sizes, int n_in,
                              void* d_out, int out_size, void* d_ws, size_t ws_size,
                              hipStream_t stream) {
  const float* inp = (const float*)d_in[0];
  const float* emb = (const float*)d_in[1];
  const float* emacs = (const float*)d_in[2];
  const float* emaw = (const float*)d_in[3];

  // Output layout (flat concat, return order):
  float* out = (float*)d_out;
  float* out_loss = out;                                   // [1]
  float* out_quant = out + 1;                              // [N*D]
  float* out_perp = out_quant + (size_t)NROWS * DDIM;      // [1]
  float* out_enc = out_perp + 1;                           // [N*K]
  float* out_emb = out_enc + (size_t)NROWS * KCODES;       // [K*D]
  float* out_ecs = out_emb + (size_t)KCODES * DDIM;        // [K]
  float* out_emaw = out_ecs + KCODES;                      // [K*D]

  // Workspace layout (~9.1 MB)
  float* ws = (float*)d_ws;
  float* dw = ws;                                          // K*D   (zeroed)
  float* counts = dw + (size_t)KCODES * DDIM;              // K     (zeroed)
  float* loss_acc = counts + KCODES;                       // 1     (zeroed, +pad)
  float* x2 = loss_acc + 4;                                // N
  float* e2 = x2 + NROWS;                                  // K
  float* pmin = e2 + KCODES;                               // N*4
  int* pidx = (int*)(pmin + (size_t)NROWS * 4);            // N*4
  int* idxb = pidx + (size_t)NROWS * 4;                    // N

  hipMemsetAsync(dw, 0, (size_t)(KCODES * DDIM + KCODES + 8) * sizeof(float), stream);
  hipMemsetAsync(out_enc, 0, (size_t)NROWS * KCODES * sizeof(float), stream);

  k_sqnorms<<<(NROWS + KCODES) / 4, 256, 0, stream>>>(inp, emb, x2, e2);
  k_argmin<<<1024, 256, 0, stream>>>(inp, emb, x2, e2, pmin, pidx);
  k_merge<<<64, 256, 0, stream>>>(pmin, pidx, idxb);
  k_scatter<<<NROWS / 4, 256, 0, stream>>>(inp, emb, idxb, out_quant, out_enc, counts, dw, loss_acc);
  k_stats<<<1, 256, 0, stream>>>(counts, emacs, loss_acc, out_loss, out_perp, out_ecs);
  k_update<<<(KCODES * DDIM) / 1024, 256, 0, stream>>>(emaw, dw, out_ecs, out_emaw, out_emb);
}

// Round 2
// 1756.434 us; speedup vs baseline: 1.0203x; 1.0203x over previous
//
#include <hip/hip_runtime.h>
#include <cstdint>
#include <cstddef>

#define NROWS 16384
#define DDIM  256
#define KCODES 8192
#define MARGIN 1.5f

typedef short bf16x8 __attribute__((ext_vector_type(8)));
typedef float f32x4 __attribute__((ext_vector_type(4)));

__device__ inline unsigned short f2bf(float f) {
  unsigned int u = __float_as_uint(f);
  return (unsigned short)((u + 0x7fffu + ((u >> 16) & 1u)) >> 16);  // RNE
}

__device__ inline void gl_lds16(const void* g, void* l) {
  __builtin_amdgcn_global_load_lds(
      (const __attribute__((address_space(1))) unsigned int*)g,
      (__attribute__((address_space(3))) unsigned int*)l, 16, 0, 0);
}

// branchless-ish top-2 insert with total order (val, then index) so butterfly
// merges converge identically on all lanes
__device__ inline void ins2(float v, int i, float& v1, int& i1, float& v2, int& i2) {
  bool b1 = (v < v1) || (v == v1 && i < i1);
  bool b2 = (v < v2) || (v == v2 && i < i2);
  if (b1) { v2 = v1; i2 = i1; v1 = v; i1 = i; }
  else if (b2) { v2 = v; i2 = i; }
}

// ---------------------------------------------------------------------------
// K0: fp32 row norms + bf16 conversion of X and E. One wave per row.
// ---------------------------------------------------------------------------
__global__ void k_prep(const float* __restrict__ inp, const float* __restrict__ emb,
                       unsigned short* __restrict__ Xb, unsigned short* __restrict__ Eb,
                       float* __restrict__ x2, float* __restrict__ e2) {
  int wave = threadIdx.x >> 6, lane = threadIdx.x & 63;
  int row = blockIdx.x * 4 + wave;
  bool isx = row < NROWS;
  const float* src = isx ? (inp + (size_t)row * DDIM) : (emb + (size_t)(row - NROWS) * DDIM);
  float4 v = ((const float4*)src)[lane];
  unsigned short* dst = isx ? (Xb + (size_t)row * DDIM) : (Eb + (size_t)(row - NROWS) * DDIM);
  ushort4 u; u.x = f2bf(v.x); u.y = f2bf(v.y); u.z = f2bf(v.z); u.w = f2bf(v.w);
  ((ushort4*)dst)[lane] = u;
  float s = v.x * v.x + v.y * v.y + v.z * v.z + v.w * v.w;
#pragma unroll
  for (int o = 32; o >= 1; o >>= 1) s += __shfl_down(s, o, 64);
  if (lane == 0) { if (isx) x2[row] = s; else e2[row - NROWS] = s; }
}

// ---------------------------------------------------------------------------
// K1: bf16 MFMA GEMM tile 128x128 (rows x codes), K=256, with fused
// d~ = x2 + e2 - 2*S epilogue and per-row top-2 (value,index) per col-block.
// Staging via global_load_lds width=16, m97 structure.
// ---------------------------------------------------------------------------
__global__ __launch_bounds__(256, 2) void k_mfma(
    const unsigned short* __restrict__ Xb, const unsigned short* __restrict__ Eb,
    const float* __restrict__ x2, const float* __restrict__ e2,
    float* __restrict__ top2v, int* __restrict__ top2i) {
  __shared__ unsigned short smA[128 * 64];  // 16 KB
  __shared__ unsigned short smB[128 * 64];  // 16 KB
  __shared__ float sx2[128];
  __shared__ float se2[128];
  __shared__ float ltv[128][2][2];
  __shared__ int   lti[128][2][2];

  const int tid = threadIdx.x;
  const int w = tid >> 6, lane = tid & 63;
  const int rt = blockIdx.x & 127, cb = blockIdx.x >> 7;
  const int row0 = rt * 128, c0 = cb * 128;
  const int rm = (w >> 1) * 64, cn = (w & 1) * 64;  // wave subtile 64x64
  const int lcol = lane & 15, quad = lane >> 4;

  if (tid < 128) sx2[tid] = x2[row0 + tid];
  else se2[tid - 128] = e2[c0 + tid - 128];

  f32x4 acc[4][4];
#pragma unroll
  for (int mi = 0; mi < 4; ++mi)
#pragma unroll
    for (int ni = 0; ni < 4; ++ni) acc[mi][ni] = (f32x4){0.f, 0.f, 0.f, 0.f};

  for (int kb = 0; kb < DDIM; kb += 64) {
    __syncthreads();  // prev compute done (also fences sx2/se2 on iter 0)
#pragma unroll
    for (int ii = 0; ii < 4; ++ii) {
      int inst = w * 4 + ii;                 // 16 instrs of 1 KB per tile
      int r8 = inst * 8 + (lane >> 3);       // row covered by this lane
      int kofs = (lane & 7) * 8;             // 8 bf16 = 16 B per lane
      gl_lds16(Xb + (size_t)(row0 + r8) * DDIM + kb + kofs, (char*)smA + inst * 1024);
      gl_lds16(Eb + (size_t)(c0 + r8) * DDIM + kb + kofs, (char*)smB + inst * 1024);
    }
    __syncthreads();
#pragma unroll
    for (int kk = 0; kk < 64; kk += 32) {
      bf16x8 a[4], b[4];
#pragma unroll
      for (int mi = 0; mi < 4; ++mi)
        a[mi] = *(const bf16x8*)&smA[(rm + mi * 16 + lcol) * 64 + kk + quad * 8];
#pragma unroll
      for (int ni = 0; ni < 4; ++ni)
        b[ni] = *(const bf16x8*)&smB[(cn + ni * 16 + lcol) * 64 + kk + quad * 8];
#pragma unroll
      for (int mi = 0; mi < 4; ++mi)
#pragma unroll
        for (int ni = 0; ni < 4; ++ni)
          acc[mi][ni] = __builtin_amdgcn_mfma_f32_16x16x32_bf16(a[mi], b[ni], acc[mi][ni], 0, 0, 0);
    }
  }

  // epilogue: per-row top-2 over this block's 128 cols
#pragma unroll
  for (int mi = 0; mi < 4; ++mi) {
#pragma unroll
    for (int r = 0; r < 4; ++r) {
      int lrow = rm + mi * 16 + quad * 4 + r;  // C/D: row=quad*4+reg, col=lane&15
      float xv = sx2[lrow];
      float v1 = 3.4e38f, v2 = 3.4e38f;
      int i1 = 0x7fffffff, i2 = 0x7fffffff;
#pragma unroll
      for (int ni = 0; ni < 4; ++ni) {
        int cl = cn + ni * 16 + lcol;
        float d = (xv + se2[cl]) - 2.0f * acc[mi][ni][r];
        ins2(d, c0 + cl, v1, i1, v2, i2);
      }
#pragma unroll
      for (int off = 1; off < 16; off <<= 1) {  // stays inside 16-lane group
        float ov1 = __shfl_xor(v1, off, 64); int oi1 = __shfl_xor(i1, off, 64);
        float ov2 = __shfl_xor(v2, off, 64); int oi2 = __shfl_xor(i2, off, 64);
        ins2(ov1, oi1, v1, i1, v2, i2);
        ins2(ov2, oi2, v1, i1, v2, i2);
      }
      if (lcol == 0) {
        ltv[lrow][w & 1][0] = v1; ltv[lrow][w & 1][1] = v2;
        lti[lrow][w & 1][0] = i1; lti[lrow][w & 1][1] = i2;
      }
    }
  }
  __syncthreads();
  if (tid < 128) {
    float v1 = ltv[tid][0][0], v2 = ltv[tid][0][1];
    int i1 = lti[tid][0][0], i2 = lti[tid][0][1];
    ins2(ltv[tid][1][0], lti[tid][1][0], v1, i1, v2, i2);
    ins2(ltv[tid][1][1], lti[tid][1][1], v1, i1, v2, i2);
    size_t o = ((size_t)(row0 + tid) * 64 + cb) * 2;
    top2v[o] = v1; top2v[o + 1] = v2;
    top2i[o] = i1; top2i[o + 1] = i2;
  }
}

// ---------------------------------------------------------------------------
// K2: per row: m~ = min over 64 blocks x top-2; exact fp32 rescore of all
// stored pairs within m~ + MARGIN; first-index tiebreak. One wave per row.
// ---------------------------------------------------------------------------
__global__ void k_select(const float* __restrict__ inp, const float* __restrict__ emb,
                         const float* __restrict__ x2, const float* __restrict__ e2,
                         const float* __restrict__ top2v, const int* __restrict__ top2i,
                         int* __restrict__ idxb) {
  int w = threadIdx.x >> 6, lane = threadIdx.x & 63;
  int row = blockIdx.x * 4 + w;
  float2 tv = *(const float2*)&top2v[((size_t)row * 64 + lane) * 2];
  int2 ti = *(const int2*)&top2i[((size_t)row * 64 + lane) * 2];
  float m = fminf(tv.x, tv.y);
#pragma unroll
  for (int o = 32; o >= 1; o >>= 1) m = fminf(m, __shfl_xor(m, o, 64));
  float thr = m + MARGIN;
  unsigned long long b0 = __ballot(tv.x <= thr);
  unsigned long long b1 = __ballot(tv.y <= thr);
  float4 x4 = *(const float4*)(inp + (size_t)row * DDIM + lane * 4);
  float x2r = x2[row];
  float bestv = 3.4e38f;
  int besti = 0x7fffffff;
  while (b0 | b1) {
    int j;
    if (b0) {
      int src = __ffsll((unsigned long long)b0) - 1; b0 &= b0 - 1;
      j = __shfl(ti.x, src, 64);
    } else {
      int src = __ffsll((unsigned long long)b1) - 1; b1 &= b1 - 1;
      j = __shfl(ti.y, src, 64);
    }
    float4 e4 = *(const float4*)(emb + (size_t)j * DDIM + lane * 4);
    float p = x4.x * e4.x + x4.y * e4.y + x4.z * e4.z + x4.w * e4.w;
#pragma unroll
    for (int o = 32; o >= 1; o >>= 1) p += __shfl_xor(p, o, 64);
    float d2 = (x2r + e2[j]) - 2.0f * p;
    if (d2 < bestv || (d2 == bestv && j < besti)) { bestv = d2; besti = j; }
  }
  if (lane == 0) idxb[row] = besti;
}

// ---------------------------------------------------------------------------
// K3: per-row scatter: quantized, one-hot, counts/dw atomics, loss partial.
// ---------------------------------------------------------------------------
__global__ void k_scatter(const float* __restrict__ inp, const float* __restrict__ emb,
                          const int* __restrict__ idxb,
                          float* __restrict__ out_quant, float* __restrict__ out_enc,
                          float* __restrict__ counts, float* __restrict__ dw,
                          float* __restrict__ loss_acc) {
  __shared__ float wsum[4];
  int wave = threadIdx.x >> 6, lane = threadIdx.x & 63;
  int row = blockIdx.x * 4 + wave;
  int j = idxb[row];
  float4 x = *(const float4*)(inp + (size_t)row * DDIM + lane * 4);
  float4 e = *(const float4*)(emb + (size_t)j * DDIM + lane * 4);
  size_t qo = (size_t)row * DDIM + lane * 4;  // out_quant only 4B aligned
  out_quant[qo + 0] = x.x + (e.x - x.x);
  out_quant[qo + 1] = x.y + (e.y - x.y);
  out_quant[qo + 2] = x.z + (e.z - x.z);
  out_quant[qo + 3] = x.w + (e.w - x.w);
  size_t dwo = (size_t)j * DDIM + lane * 4;
  atomicAdd(&dw[dwo + 0], x.x);
  atomicAdd(&dw[dwo + 1], x.y);
  atomicAdd(&dw[dwo + 2], x.z);
  atomicAdd(&dw[dwo + 3], x.w);
  float d0 = e.x - x.x, d1 = e.y - x.y, d2 = e.z - x.z, d3 = e.w - x.w;
  float s = d0 * d0 + d1 * d1 + d2 * d2 + d3 * d3;
#pragma unroll
  for (int o = 32; o >= 1; o >>= 1) s += __shfl_down(s, o, 64);
  if (lane == 0) {
    atomicAdd(&counts[j], 1.0f);
    out_enc[(size_t)row * KCODES + j] = 1.0f;
    wsum[wave] = s;
  }
  __syncthreads();
  if (threadIdx.x == 0) atomicAdd(loss_acc, wsum[0] + wsum[1] + wsum[2] + wsum[3]);
}

// ---------------------------------------------------------------------------
// K4: single block: n, normalized ecs, perplexity, loss.
// ---------------------------------------------------------------------------
__global__ void k_stats(const float* __restrict__ counts, const float* __restrict__ ema_cs,
                        const float* __restrict__ loss_acc,
                        float* __restrict__ out_loss, float* __restrict__ out_perp,
                        float* __restrict__ out_ecs) {
  __shared__ float red[8];
  int tid = threadIdx.x;
  float ln = 0.0f, lp = 0.0f;
  for (int k = tid; k < KCODES; k += 256) {
    float c = counts[k];
    float er = ema_cs[k] * 0.99f + 0.01f * c;
    ln += er;
    float p = c * (1.0f / 16384.0f);
    lp += p * logf(p + 1e-10f);
  }
  int lane = tid & 63, wave = tid >> 6;
#pragma unroll
  for (int o = 32; o >= 1; o >>= 1) {
    ln += __shfl_down(ln, o, 64);
    lp += __shfl_down(lp, o, 64);
  }
  if (lane == 0) { red[wave] = ln; red[wave + 4] = lp; }
  __syncthreads();
  float n = red[0] + red[1] + red[2] + red[3];
  float plsum = red[4] + red[5] + red[6] + red[7];
  float denom = n + 0.08192f;  // n + K*EPSILON
  for (int k = tid; k < KCODES; k += 256) {
    float c = counts[k];
    float er = ema_cs[k] * 0.99f + 0.01f * c;
    out_ecs[k] = (er + 1e-5f) / denom * n;
  }
  if (tid == 0) {
    out_loss[0] = 0.25f * (loss_acc[0] / 4194304.0f);
    out_perp[0] = expf(-plsum);
  }
}

// ---------------------------------------------------------------------------
// K5: EMA update + new embedding.
// ---------------------------------------------------------------------------
__global__ void k_update(const float* __restrict__ ema_w, const float* __restrict__ dw,
                         const float* __restrict__ ecs,
                         float* __restrict__ out_emaw, float* __restrict__ out_emb) {
  size_t i = ((size_t)blockIdx.x * blockDim.x + threadIdx.x) * 4;
  int k = (int)(i >> 8);
  float4 w = *(const float4*)(ema_w + i);
  float4 d = *(const float4*)(dw + i);
  float ec = ecs[k];
  float nw0 = w.x * 0.99f + 0.01f * d.x;
  float nw1 = w.y * 0.99f + 0.01f * d.y;
  float nw2 = w.z * 0.99f + 0.01f * d.z;
  float nw3 = w.w * 0.99f + 0.01f * d.w;
  *(float2*)(out_emaw + i) = make_float2(nw0, nw1);
  *(float2*)(out_emaw + i + 2) = make_float2(nw2, nw3);
  *(float2*)(out_emb + i) = make_float2(nw0 / ec, nw1 / ec);
  *(float2*)(out_emb + i + 2) = make_float2(nw2 / ec, nw3 / ec);
}

extern "C" void kernel_launch(void* const* d_in, const int* in_sizes, int n_in,
                              void* d_out, int out_size, void* d_ws, size_t ws_size,
                              hipStream_t stream) {
  const float* inp = (const float*)d_in[0];
  const float* emb = (const float*)d_in[1];
  const float* emacs = (const float*)d_in[2];
  const float* emaw = (const float*)d_in[3];

  float* out = (float*)d_out;
  float* out_loss = out;                                   // [1]
  float* out_quant = out + 1;                              // [N*D]
  float* out_perp = out_quant + (size_t)NROWS * DDIM;      // [1]
  float* out_enc = out_perp + 1;                           // [N*K]
  float* out_emb = out_enc + (size_t)NROWS * KCODES;       // [K*D]
  float* out_ecs = out_emb + (size_t)KCODES * DDIM;        // [K]
  float* out_emaw = out_ecs + KCODES;                      // [K*D]

  // Workspace (~36.4 MB)
  char* p = (char*)d_ws;
  unsigned short* Xb = (unsigned short*)p; p += (size_t)NROWS * DDIM * 2;   // 8 MB
  unsigned short* Eb = (unsigned short*)p; p += (size_t)KCODES * DDIM * 2;  // 4 MB
  float* x2 = (float*)p; p += (size_t)NROWS * 4;
  float* e2 = (float*)p; p += (size_t)KCODES * 4;
  float* top2v = (float*)p; p += (size_t)NROWS * 64 * 2 * 4;                // 8 MB
  int* top2i = (int*)p; p += (size_t)NROWS * 64 * 2 * 4;                    // 8 MB
  float* dw = (float*)p; p += (size_t)KCODES * DDIM * 4;                    // 8 MB
  float* counts = (float*)p; p += (size_t)KCODES * 4;
  float* loss_acc = (float*)p; p += 16;
  int* idxb = (int*)p; p += (size_t)NROWS * 4;

  hipMemsetAsync(dw, 0, ((size_t)KCODES * DDIM + KCODES + 4) * sizeof(float), stream);
  hipMemsetAsync(out_enc, 0, (size_t)NROWS * KCODES * sizeof(float), stream);

  k_prep<<<(NROWS + KCODES) / 4, 256, 0, stream>>>(inp, emb, Xb, Eb, x2, e2);
  k_mfma<<<8192, 256, 0, stream>>>(Xb, Eb, x2, e2, top2v, top2i);
  k_select<<<NROWS / 4, 256, 0, stream>>>(inp, emb, x2, e2, top2v, top2i, idxb);
  k_scatter<<<NROWS / 4, 256, 0, stream>>>(inp, emb, idxb, out_quant, out_enc, counts, dw, loss_acc);
  k_stats<<<1, 256, 0, stream>>>(counts, emacs, loss_acc, out_loss, out_perp, out_ecs);
  k_update<<<(KCODES * DDIM) / 1024, 256, 0, stream>>>(emaw, dw, out_ecs, out_emaw, out_emb);
}

// Round 3
// 1355.615 us; speedup vs baseline: 1.3220x; 1.2957x over previous
//
#include <hip/hip_runtime.h>
#include <cstdint>
#include <cstddef>

#define NROWS 16384
#define DDIM  256
#define KCODES 8192
#define MARGIN 1.5f

typedef short bf16x8 __attribute__((ext_vector_type(8)));
typedef float f32x4 __attribute__((ext_vector_type(4)));

__device__ inline unsigned short f2bf(float f) {
  unsigned int u = __float_as_uint(f);
  return (unsigned short)((u + 0x7fffu + ((u >> 16) & 1u)) >> 16);  // RNE
}

// top-2 insert with total order (val, then index): first-occurrence semantics
__device__ inline void ins2(float v, int i, float& v1, int& i1, float& v2, int& i2) {
  bool b1 = (v < v1) || (v == v1 && i < i1);
  bool b2 = (v < v2) || (v == v2 && i < i2);
  if (b1) { v2 = v1; i2 = i1; v1 = v; i1 = i; }
  else if (b2) { v2 = v; i2 = i; }
}

// ---------------------------------------------------------------------------
// K0: X rows -> Xb (bf16 row-major) + x2 ; E rows -> Ebt (bf16, MFMA B-frag
// layout: elem(c,k) at ct*4096 + kq*512 + lc*32 + j, ct=c>>4, lc=c&15,
// kq=k>>5, j=k&31) + e2. One wave per row.
// ---------------------------------------------------------------------------
__global__ void k_prep(const float* __restrict__ inp, const float* __restrict__ emb,
                       unsigned short* __restrict__ Xb, unsigned short* __restrict__ Ebt,
                       float* __restrict__ x2, float* __restrict__ e2) {
  int wave = threadIdx.x >> 6, lane = threadIdx.x & 63;
  int row = blockIdx.x * 4 + wave;
  bool isx = row < NROWS;
  const float* src = isx ? (inp + (size_t)row * DDIM) : (emb + (size_t)(row - NROWS) * DDIM);
  float4 v = ((const float4*)src)[lane];
  ushort4 u; u.x = f2bf(v.x); u.y = f2bf(v.y); u.z = f2bf(v.z); u.w = f2bf(v.w);
  if (isx) {
    *(ushort4*)&Xb[(size_t)row * DDIM + lane * 4] = u;
  } else {
    int c = row - NROWS, ct = c >> 4, lc = c & 15;
    size_t off = (size_t)ct * 4096 + (lane >> 3) * 512 + lc * 32 + (lane & 7) * 4;
    *(ushort4*)&Ebt[off] = u;
  }
  float s = v.x * v.x + v.y * v.y + v.z * v.z + v.w * v.w;
#pragma unroll
  for (int o = 32; o >= 1; o >>= 1) s += __shfl_down(s, o, 64);
  if (lane == 0) { if (isx) x2[row] = s; else e2[row - NROWS] = s; }
}

// ---------------------------------------------------------------------------
// K1: barrier-free distance scan. Wave owns 32 rows (A-frags resident in
// VGPRs, K=256 fully unrolled) and one 1024-col slice of E; streams B-frags
// global->reg (coalesced dwordx4 from Ebt), MFMA 16x16x32, running per-thread
// top-2 of d' = e2 - 2*dot (x2 is row-constant: argmin-invariant).
// 16-lane butterfly once at the end; writes top-2 per (row, slice).
// ---------------------------------------------------------------------------
__global__ __launch_bounds__(256) void k_dist(
    const unsigned short* __restrict__ Xb, const unsigned short* __restrict__ Ebt,
    const float* __restrict__ e2,
    float* __restrict__ candv, int* __restrict__ candi) {
  const int w = threadIdx.x >> 6, lane = threadIdx.x & 63;
  const int lcol = lane & 15, quad = lane >> 4;
  const int row0 = (blockIdx.x >> 3) * 128 + w * 32;
  const int slice = blockIdx.x & 7;

  bf16x8 A[2][8];
#pragma unroll
  for (int mi = 0; mi < 2; ++mi)
#pragma unroll
    for (int kq = 0; kq < 8; ++kq)
      A[mi][kq] = *(const bf16x8*)&Xb[(size_t)(row0 + mi * 16 + lcol) * DDIM + kq * 32 + quad * 8];

  float v1[8], v2[8];
  int i1[8], i2[8];
#pragma unroll
  for (int s = 0; s < 8; ++s) { v1[s] = 3.4e38f; v2[s] = 3.4e38f; i1[s] = 0x7fffffff; i2[s] = 0x7fffffff; }

  const unsigned short* Bp = Ebt + (size_t)slice * 64 * 4096;
  const int laneoff = lcol * 32 + quad * 8;

  bf16x8 B[8];
#pragma unroll
  for (int kq = 0; kq < 8; ++kq) B[kq] = *(const bf16x8*)&Bp[kq * 512 + laneoff];
  float e2c = e2[slice * 1024 + lcol];

  for (int t = 0; t < 64; ++t) {
    bf16x8 Bn[8];
    float e2n = 0.0f;
    if (t < 63) {  // prefetch next tile while MFMA runs
      const unsigned short* Bq = Bp + (size_t)(t + 1) * 4096;
#pragma unroll
      for (int kq = 0; kq < 8; ++kq) Bn[kq] = *(const bf16x8*)&Bq[kq * 512 + laneoff];
      e2n = e2[slice * 1024 + (t + 1) * 16 + lcol];
    }
    f32x4 acc0 = {0.f, 0.f, 0.f, 0.f}, acc1 = {0.f, 0.f, 0.f, 0.f};
#pragma unroll
    for (int kq = 0; kq < 8; ++kq) {
      acc0 = __builtin_amdgcn_mfma_f32_16x16x32_bf16(A[0][kq], B[kq], acc0, 0, 0, 0);
      acc1 = __builtin_amdgcn_mfma_f32_16x16x32_bf16(A[1][kq], B[kq], acc1, 0, 0, 0);
    }
    const int col = slice * 1024 + t * 16 + lcol;
#pragma unroll
    for (int r = 0; r < 4; ++r) {
      float d0 = fmaf(-2.0f, acc0[r], e2c);
      ins2(d0, col, v1[r], i1[r], v2[r], i2[r]);
      float d1 = fmaf(-2.0f, acc1[r], e2c);
      ins2(d1, col, v1[4 + r], i1[4 + r], v2[4 + r], i2[4 + r]);
    }
    if (t < 63) {
#pragma unroll
      for (int kq = 0; kq < 8; ++kq) B[kq] = Bn[kq];
      e2c = e2n;
    }
  }

#pragma unroll
  for (int s = 0; s < 8; ++s) {
    float a1 = v1[s], a2 = v2[s];
    int b1 = i1[s], b2 = i2[s];
#pragma unroll
    for (int off = 1; off < 16; off <<= 1) {  // stays inside 16-lane group
      float o1 = __shfl_xor(a1, off, 64); int p1 = __shfl_xor(b1, off, 64);
      float o2 = __shfl_xor(a2, off, 64); int p2 = __shfl_xor(b2, off, 64);
      ins2(o1, p1, a1, b1, a2, b2);
      ins2(o2, p2, a1, b1, a2, b2);
    }
    if (lcol == 0) {
      int mi = s >> 2, r = s & 3;
      int row = row0 + mi * 16 + quad * 4 + r;  // C/D: row=quad*4+reg, col=lane&15
      size_t o = ((size_t)row * 8 + slice) * 2;
      candv[o] = a1; candv[o + 1] = a2;
      candi[o] = b1; candi[o + 1] = b2;
    }
  }
}

// ---------------------------------------------------------------------------
// K2: per row: global approx min over 16 candidates; exact fp32 rescore of
// all candidates within min + MARGIN; first-index tiebreak. One wave per row.
// ---------------------------------------------------------------------------
__global__ void k_select(const float* __restrict__ inp, const float* __restrict__ emb,
                         const float* __restrict__ x2, const float* __restrict__ e2,
                         const float* __restrict__ candv, const int* __restrict__ candi,
                         int* __restrict__ idxb) {
  int w = threadIdx.x >> 6, lane = threadIdx.x & 63;
  int row = blockIdx.x * 4 + w;
  float cv = 3.4e38f;
  int ci = 0x7fffffff;
  if (lane < 16) { cv = candv[(size_t)row * 16 + lane]; ci = candi[(size_t)row * 16 + lane]; }
  float m = cv;
#pragma unroll
  for (int o = 32; o >= 1; o >>= 1) m = fminf(m, __shfl_xor(m, o, 64));
  float thr = m + MARGIN;
  unsigned long long b = __ballot(cv <= thr);
  float4 x4 = *(const float4*)(inp + (size_t)row * DDIM + lane * 4);
  float x2r = x2[row];
  float bestv = 3.4e38f;
  int besti = 0x7fffffff;
  while (b) {
    int src = __ffsll(b) - 1; b &= b - 1;
    int j = __shfl(ci, src, 64);
    float4 e4 = *(const float4*)(emb + (size_t)j * DDIM + lane * 4);
    float p = x4.x * e4.x + x4.y * e4.y + x4.z * e4.z + x4.w * e4.w;
#pragma unroll
    for (int o = 32; o >= 1; o >>= 1) p += __shfl_xor(p, o, 64);
    float d2 = (x2r + e2[j]) - 2.0f * p;  // mirror reference formula
    if (d2 < bestv || (d2 == bestv && j < besti)) { bestv = d2; besti = j; }
  }
  if (lane == 0) idxb[row] = besti;
}

// ---------------------------------------------------------------------------
// K3: per-row scatter: quantized, one-hot, counts/dw atomics, loss partial.
// ---------------------------------------------------------------------------
__global__ void k_scatter(const float* __restrict__ inp, const float* __restrict__ emb,
                          const int* __restrict__ idxb,
                          float* __restrict__ out_quant, float* __restrict__ out_enc,
                          float* __restrict__ counts, float* __restrict__ dw,
                          float* __restrict__ loss_acc) {
  __shared__ float wsum[4];
  int wave = threadIdx.x >> 6, lane = threadIdx.x & 63;
  int row = blockIdx.x * 4 + wave;
  int j = idxb[row];
  float4 x = *(const float4*)(inp + (size_t)row * DDIM + lane * 4);
  float4 e = *(const float4*)(emb + (size_t)j * DDIM + lane * 4);
  size_t qo = (size_t)row * DDIM + lane * 4;  // out_quant only 4B aligned
  out_quant[qo + 0] = x.x + (e.x - x.x);
  out_quant[qo + 1] = x.y + (e.y - x.y);
  out_quant[qo + 2] = x.z + (e.z - x.z);
  out_quant[qo + 3] = x.w + (e.w - x.w);
  size_t dwo = (size_t)j * DDIM + lane * 4;
  atomicAdd(&dw[dwo + 0], x.x);
  atomicAdd(&dw[dwo + 1], x.y);
  atomicAdd(&dw[dwo + 2], x.z);
  atomicAdd(&dw[dwo + 3], x.w);
  float d0 = e.x - x.x, d1 = e.y - x.y, d2 = e.z - x.z, d3 = e.w - x.w;
  float s = d0 * d0 + d1 * d1 + d2 * d2 + d3 * d3;
#pragma unroll
  for (int o = 32; o >= 1; o >>= 1) s += __shfl_down(s, o, 64);
  if (lane == 0) {
    atomicAdd(&counts[j], 1.0f);
    out_enc[(size_t)row * KCODES + j] = 1.0f;
    wsum[wave] = s;
  }
  __syncthreads();
  if (threadIdx.x == 0) atomicAdd(loss_acc, wsum[0] + wsum[1] + wsum[2] + wsum[3]);
}

// ---------------------------------------------------------------------------
// K4: single block: n, normalized ecs, perplexity, loss.
// ---------------------------------------------------------------------------
__global__ void k_stats(const float* __restrict__ counts, const float* __restrict__ ema_cs,
                        const float* __restrict__ loss_acc,
                        float* __restrict__ out_loss, float* __restrict__ out_perp,
                        float* __restrict__ out_ecs) {
  __shared__ float red[8];
  int tid = threadIdx.x;
  float ln = 0.0f, lp = 0.0f;
  for (int k = tid; k < KCODES; k += 256) {
    float c = counts[k];
    float er = ema_cs[k] * 0.99f + 0.01f * c;
    ln += er;
    float p = c * (1.0f / 16384.0f);
    lp += p * logf(p + 1e-10f);
  }
  int lane = tid & 63, wave = tid >> 6;
#pragma unroll
  for (int o = 32; o >= 1; o >>= 1) {
    ln += __shfl_down(ln, o, 64);
    lp += __shfl_down(lp, o, 64);
  }
  if (lane == 0) { red[wave] = ln; red[wave + 4] = lp; }
  __syncthreads();
  float n = red[0] + red[1] + red[2] + red[3];
  float plsum = red[4] + red[5] + red[6] + red[7];
  float denom = n + 0.08192f;  // n + K*EPSILON
  for (int k = tid; k < KCODES; k += 256) {
    float c = counts[k];
    float er = ema_cs[k] * 0.99f + 0.01f * c;
    out_ecs[k] = (er + 1e-5f) / denom * n;  // mirror reference op order
  }
  if (tid == 0) {
    out_loss[0] = 0.25f * (loss_acc[0] / 4194304.0f);  // /(N*D)
    out_perp[0] = expf(-plsum);
  }
}

// ---------------------------------------------------------------------------
// K5: EMA update + new embedding. d_out only 4B-aligned overall -> float2 ok
// at these offsets (even element offsets).
// ---------------------------------------------------------------------------
__global__ void k_update(const float* __restrict__ ema_w, const float* __restrict__ dw,
                         const float* __restrict__ ecs,
                         float* __restrict__ out_emaw, float* __restrict__ out_emb) {
  size_t i = ((size_t)blockIdx.x * blockDim.x + threadIdx.x) * 4;
  int k = (int)(i >> 8);
  float4 w = *(const float4*)(ema_w + i);
  float4 d = *(const float4*)(dw + i);
  float ec = ecs[k];
  float nw0 = w.x * 0.99f + 0.01f * d.x;
  float nw1 = w.y * 0.99f + 0.01f * d.y;
  float nw2 = w.z * 0.99f + 0.01f * d.z;
  float nw3 = w.w * 0.99f + 0.01f * d.w;
  *(float2*)(out_emaw + i) = make_float2(nw0, nw1);
  *(float2*)(out_emaw + i + 2) = make_float2(nw2, nw3);
  *(float2*)(out_emb + i) = make_float2(nw0 / ec, nw1 / ec);
  *(float2*)(out_emb + i + 2) = make_float2(nw2 / ec, nw3 / ec);
}

extern "C" void kernel_launch(void* const* d_in, const int* in_sizes, int n_in,
                              void* d_out, int out_size, void* d_ws, size_t ws_size,
                              hipStream_t stream) {
  const float* inp = (const float*)d_in[0];
  const float* emb = (const float*)d_in[1];
  const float* emacs = (const float*)d_in[2];
  const float* emaw = (const float*)d_in[3];

  float* out = (float*)d_out;
  float* out_loss = out;                                   // [1]
  float* out_quant = out + 1;                              // [N*D]
  float* out_perp = out_quant + (size_t)NROWS * DDIM;      // [1]
  float* out_enc = out_perp + 1;                           // [N*K]
  float* out_emb = out_enc + (size_t)NROWS * KCODES;       // [K*D]
  float* out_ecs = out_emb + (size_t)KCODES * DDIM;        // [K]
  float* out_emaw = out_ecs + KCODES;                      // [K*D]

  // Workspace (~22.3 MB)
  char* p = (char*)d_ws;
  unsigned short* Xb = (unsigned short*)p; p += (size_t)NROWS * DDIM * 2;   // 8 MB
  unsigned short* Ebt = (unsigned short*)p; p += (size_t)KCODES * DDIM * 2; // 4 MB
  float* x2 = (float*)p; p += (size_t)NROWS * 4;
  float* e2 = (float*)p; p += (size_t)KCODES * 4;
  float* candv = (float*)p; p += (size_t)NROWS * 16 * 4;                    // 1 MB
  int* candi = (int*)p; p += (size_t)NROWS * 16 * 4;                        // 1 MB
  float* dw = (float*)p; p += (size_t)KCODES * DDIM * 4;                    // 8 MB
  float* counts = (float*)p; p += (size_t)KCODES * 4;
  float* loss_acc = (float*)p; p += 16;
  int* idxb = (int*)p; p += (size_t)NROWS * 4;

  hipMemsetAsync(dw, 0, ((size_t)KCODES * DDIM + KCODES + 4) * sizeof(float), stream);
  hipMemsetAsync(out_enc, 0, (size_t)NROWS * KCODES * sizeof(float), stream);

  k_prep<<<(NROWS + KCODES) / 4, 256, 0, stream>>>(inp, emb, Xb, Ebt, x2, e2);
  k_dist<<<1024, 256, 0, stream>>>(Xb, Ebt, e2, candv, candi);
  k_select<<<NROWS / 4, 256, 0, stream>>>(inp, emb, x2, e2, candv, candi, idxb);
  k_scatter<<<NROWS / 4, 256, 0, stream>>>(inp, emb, idxb, out_quant, out_enc, counts, dw, loss_acc);
  k_stats<<<1, 256, 0, stream>>>(counts, emacs, loss_acc, out_loss, out_perp, out_ecs);
  k_update<<<(KCODES * DDIM) / 1024, 256, 0, stream>>>(emaw, dw, out_ecs, out_emaw, out_emb);
}

// Round 4
// 964.931 us; speedup vs baseline: 1.8572x; 1.4049x over previous
//
#include <hip/hip_runtime.h>
#include <cstdint>
#include <cstddef>

#define NROWS 16384
#define DDIM  256
#define KCODES 8192
#define MARGIN 1.5f

typedef short bf16x8 __attribute__((ext_vector_type(8)));
typedef float f32x4 __attribute__((ext_vector_type(4)));

__device__ inline unsigned short f2bf(float f) {
  unsigned int u = __float_as_uint(f);
  return (unsigned short)((u + 0x7fffu + ((u >> 16) & 1u)) >> 16);  // RNE
}

// full top-2 insert with (val, index) total order — used only in butterflies
__device__ inline void ins2(float v, int i, float& v1, int& i1, float& v2, int& i2) {
  bool b1 = (v < v1) || (v == v1 && i < i1);
  bool b2 = (v < v2) || (v == v2 && i < i2);
  if (b1) { v2 = v1; i2 = i1; v1 = v; i1 = i; }
  else if (b2) { v2 = v; i2 = i; }
}

// ---------------------------------------------------------------------------
// K0: X rows -> Xb (bf16 row-major) + x2 ; E rows -> Ebt (bf16, MFMA B-frag
// layout: elem(c,k) at ct*4096 + kq*512 + lc*32 + (k&31)) + e2. One wave/row.
// ---------------------------------------------------------------------------
__global__ void k_prep(const float* __restrict__ inp, const float* __restrict__ emb,
                       unsigned short* __restrict__ Xb, unsigned short* __restrict__ Ebt,
                       float* __restrict__ x2, float* __restrict__ e2) {
  int wave = threadIdx.x >> 6, lane = threadIdx.x & 63;
  int row = blockIdx.x * 4 + wave;
  bool isx = row < NROWS;
  const float* src = isx ? (inp + (size_t)row * DDIM) : (emb + (size_t)(row - NROWS) * DDIM);
  float4 v = ((const float4*)src)[lane];
  ushort4 u; u.x = f2bf(v.x); u.y = f2bf(v.y); u.z = f2bf(v.z); u.w = f2bf(v.w);
  if (isx) {
    *(ushort4*)&Xb[(size_t)row * DDIM + lane * 4] = u;
  } else {
    int c = row - NROWS, ct = c >> 4, lc = c & 15;
    size_t off = (size_t)ct * 4096 + (lane >> 3) * 512 + lc * 32 + (lane & 7) * 4;
    *(ushort4*)&Ebt[off] = u;
  }
  float s = v.x * v.x + v.y * v.y + v.z * v.z + v.w * v.w;
#pragma unroll
  for (int o = 32; o >= 1; o >>= 1) s += __shfl_down(s, o, 64);
  if (lane == 0) { if (isx) x2[row] = s; else e2[row - NROWS] = s; }
}

// ---------------------------------------------------------------------------
// K1: barrier-free distance scan, fully scalarized (no loop-carried arrays ->
// no scratch). Wave owns 32 rows (A-frags in named VGPRs) and one 1024-col
// slice; streams B-frags global->reg, 16 MFMA/t, running per-row top-2 of
// d' = e2 - 2*dot (x2 row-constant, argmin-invariant).
// ---------------------------------------------------------------------------
#define DECL_SLOT(s) \
  float v1_##s = 3.4e38f, v2_##s = 3.4e38f; \
  int i1_##s = 0x7fffffff, i2_##s = 0x7fffffff;

#define UPD(s, a) { \
  float d = fmaf(-2.0f, (a), e2c); \
  if (d < v1_##s) { v2_##s = v1_##s; i2_##s = i1_##s; v1_##s = d; i1_##s = col; } \
  else if (d < v2_##s) { v2_##s = d; i2_##s = col; } }

#define RED_SLOT(s, mi, r) { \
  float a1 = v1_##s, a2 = v2_##s; int b1 = i1_##s, b2 = i2_##s; \
  for (int off = 1; off < 16; off <<= 1) { \
    float o1 = __shfl_xor(a1, off, 64); int p1 = __shfl_xor(b1, off, 64); \
    float o2 = __shfl_xor(a2, off, 64); int p2 = __shfl_xor(b2, off, 64); \
    ins2(o1, p1, a1, b1, a2, b2); ins2(o2, p2, a1, b1, a2, b2); } \
  if (lcol == 0) { \
    int row = row0 + (mi) * 16 + quad * 4 + (r); \
    size_t o = ((size_t)row * 8 + slice) * 2; \
    candv[o] = a1; candv[o + 1] = a2; candi[o] = b1; candi[o + 1] = b2; } }

__global__ __launch_bounds__(256, 2) void k_dist(
    const unsigned short* __restrict__ Xb, const unsigned short* __restrict__ Ebt,
    const float* __restrict__ e2,
    float* __restrict__ candv, int* __restrict__ candi) {
  const int lane = threadIdx.x & 63;
  const int w = threadIdx.x >> 6;
  const int lcol = lane & 15, quad = lane >> 4;
  const int row0 = (blockIdx.x >> 3) * 128 + w * 32;
  const int slice = blockIdx.x & 7;

  const unsigned short* ApA = Xb + (size_t)(row0 + lcol) * DDIM + quad * 8;
  const unsigned short* ApB = ApA + 16 * DDIM;
#define DECL_A(q) \
  bf16x8 A0_##q = *(const bf16x8*)(ApA + (q) * 32); \
  bf16x8 A1_##q = *(const bf16x8*)(ApB + (q) * 32);
  DECL_A(0) DECL_A(1) DECL_A(2) DECL_A(3) DECL_A(4) DECL_A(5) DECL_A(6) DECL_A(7)

  DECL_SLOT(0) DECL_SLOT(1) DECL_SLOT(2) DECL_SLOT(3)
  DECL_SLOT(4) DECL_SLOT(5) DECL_SLOT(6) DECL_SLOT(7)

  const unsigned short* Bbase = Ebt + (size_t)slice * 64 * 4096 + lcol * 32 + quad * 8;
  const float* e2p = e2 + slice * 1024 + lcol;
  const int colbase = slice * 1024 + lcol;

#pragma unroll 2
  for (int t = 0; t < 64; ++t) {
    const unsigned short* Bt = Bbase + (size_t)t * 4096;
    bf16x8 B0 = *(const bf16x8*)(Bt);
    bf16x8 B1 = *(const bf16x8*)(Bt + 512);
    bf16x8 B2 = *(const bf16x8*)(Bt + 1024);
    bf16x8 B3 = *(const bf16x8*)(Bt + 1536);
    bf16x8 B4 = *(const bf16x8*)(Bt + 2048);
    bf16x8 B5 = *(const bf16x8*)(Bt + 2560);
    bf16x8 B6 = *(const bf16x8*)(Bt + 3072);
    bf16x8 B7 = *(const bf16x8*)(Bt + 3584);
    float e2c = e2p[t * 16];
    f32x4 acc0 = {0.f, 0.f, 0.f, 0.f};
    f32x4 acc1 = {0.f, 0.f, 0.f, 0.f};
#define MM(q) \
    acc0 = __builtin_amdgcn_mfma_f32_16x16x32_bf16(A0_##q, B##q, acc0, 0, 0, 0); \
    acc1 = __builtin_amdgcn_mfma_f32_16x16x32_bf16(A1_##q, B##q, acc1, 0, 0, 0);
    MM(0) MM(1) MM(2) MM(3) MM(4) MM(5) MM(6) MM(7)
#undef MM
    const int col = colbase + t * 16;
    UPD(0, acc0[0]) UPD(1, acc0[1]) UPD(2, acc0[2]) UPD(3, acc0[3])
    UPD(4, acc1[0]) UPD(5, acc1[1]) UPD(6, acc1[2]) UPD(7, acc1[3])
  }

  // C/D layout: row = quad*4 + reg, col = lane&15
  RED_SLOT(0, 0, 0) RED_SLOT(1, 0, 1) RED_SLOT(2, 0, 2) RED_SLOT(3, 0, 3)
  RED_SLOT(4, 1, 0) RED_SLOT(5, 1, 1) RED_SLOT(6, 1, 2) RED_SLOT(7, 1, 3)
}

// ---------------------------------------------------------------------------
// K2: per row: approx min over 16 candidates; exact fp32 rescore of all
// candidates within min + MARGIN; first-index tiebreak. One wave per row.
// ---------------------------------------------------------------------------
__global__ void k_select(const float* __restrict__ inp, const float* __restrict__ emb,
                         const float* __restrict__ x2, const float* __restrict__ e2,
                         const float* __restrict__ candv, const int* __restrict__ candi,
                         int* __restrict__ idxb) {
  int w = threadIdx.x >> 6, lane = threadIdx.x & 63;
  int row = blockIdx.x * 4 + w;
  float cv = 3.4e38f;
  int ci = 0x7fffffff;
  if (lane < 16) { cv = candv[(size_t)row * 16 + lane]; ci = candi[(size_t)row * 16 + lane]; }
  float m = cv;
#pragma unroll
  for (int o = 32; o >= 1; o >>= 1) m = fminf(m, __shfl_xor(m, o, 64));
  float thr = m + MARGIN;
  unsigned long long b = __ballot(cv <= thr);
  float4 x4 = *(const float4*)(inp + (size_t)row * DDIM + lane * 4);
  float x2r = x2[row];
  float bestv = 3.4e38f;
  int besti = 0x7fffffff;
  while (b) {
    int src = __ffsll(b) - 1; b &= b - 1;
    int j = __shfl(ci, src, 64);
    float4 e4 = *(const float4*)(emb + (size_t)j * DDIM + lane * 4);
    float p = x4.x * e4.x + x4.y * e4.y + x4.z * e4.z + x4.w * e4.w;
#pragma unroll
    for (int o = 32; o >= 1; o >>= 1) p += __shfl_xor(p, o, 64);
    float d2 = (x2r + e2[j]) - 2.0f * p;  // mirror reference formula
    if (d2 < bestv || (d2 == bestv && j < besti)) { bestv = d2; besti = j; }
  }
  if (lane == 0) idxb[row] = besti;
}

// ---------------------------------------------------------------------------
// K3: per-row scatter: quantized, one-hot, counts/dw atomics, loss partial.
// ---------------------------------------------------------------------------
__global__ void k_scatter(const float* __restrict__ inp, const float* __restrict__ emb,
                          const int* __restrict__ idxb,
                          float* __restrict__ out_quant, float* __restrict__ out_enc,
                          float* __restrict__ counts, float* __restrict__ dw,
                          float* __restrict__ loss_acc) {
  __shared__ float wsum[4];
  int wave = threadIdx.x >> 6, lane = threadIdx.x & 63;
  int row = blockIdx.x * 4 + wave;
  int j = idxb[row];
  float4 x = *(const float4*)(inp + (size_t)row * DDIM + lane * 4);
  float4 e = *(const float4*)(emb + (size_t)j * DDIM + lane * 4);
  size_t qo = (size_t)row * DDIM + lane * 4;  // out_quant only 4B aligned
  out_quant[qo + 0] = x.x + (e.x - x.x);
  out_quant[qo + 1] = x.y + (e.y - x.y);
  out_quant[qo + 2] = x.z + (e.z - x.z);
  out_quant[qo + 3] = x.w + (e.w - x.w);
  size_t dwo = (size_t)j * DDIM + lane * 4;
  atomicAdd(&dw[dwo + 0], x.x);
  atomicAdd(&dw[dwo + 1], x.y);
  atomicAdd(&dw[dwo + 2], x.z);
  atomicAdd(&dw[dwo + 3], x.w);
  float d0 = e.x - x.x, d1 = e.y - x.y, d2 = e.z - x.z, d3 = e.w - x.w;
  float s = d0 * d0 + d1 * d1 + d2 * d2 + d3 * d3;
#pragma unroll
  for (int o = 32; o >= 1; o >>= 1) s += __shfl_down(s, o, 64);
  if (lane == 0) {
    atomicAdd(&counts[j], 1.0f);
    out_enc[(size_t)row * KCODES + j] = 1.0f;
    wsum[wave] = s;
  }
  __syncthreads();
  if (threadIdx.x == 0) atomicAdd(loss_acc, wsum[0] + wsum[1] + wsum[2] + wsum[3]);
}

// ---------------------------------------------------------------------------
// K4: single block: n, normalized ecs, perplexity, loss.
// ---------------------------------------------------------------------------
__global__ void k_stats(const float* __restrict__ counts, const float* __restrict__ ema_cs,
                        const float* __restrict__ loss_acc,
                        float* __restrict__ out_loss, float* __restrict__ out_perp,
                        float* __restrict__ out_ecs) {
  __shared__ float red[8];
  int tid = threadIdx.x;
  float ln = 0.0f, lp = 0.0f;
  for (int k = tid; k < KCODES; k += 256) {
    float c = counts[k];
    float er = ema_cs[k] * 0.99f + 0.01f * c;
    ln += er;
    float p = c * (1.0f / 16384.0f);
    lp += p * logf(p + 1e-10f);
  }
  int lane = tid & 63, wave = tid >> 6;
#pragma unroll
  for (int o = 32; o >= 1; o >>= 1) {
    ln += __shfl_down(ln, o, 64);
    lp += __shfl_down(lp, o, 64);
  }
  if (lane == 0) { red[wave] = ln; red[wave + 4] = lp; }
  __syncthreads();
  float n = red[0] + red[1] + red[2] + red[3];
  float plsum = red[4] + red[5] + red[6] + red[7];
  float denom = n + 0.08192f;  // n + K*EPSILON
  for (int k = tid; k < KCODES; k += 256) {
    float c = counts[k];
    float er = ema_cs[k] * 0.99f + 0.01f * c;
    out_ecs[k] = (er + 1e-5f) / denom * n;  // mirror reference op order
  }
  if (tid == 0) {
    out_loss[0] = 0.25f * (loss_acc[0] / 4194304.0f);  // /(N*D)
    out_perp[0] = expf(-plsum);
  }
}

// ---------------------------------------------------------------------------
// K5: EMA update + new embedding (float2: outputs 8B-aligned).
// ---------------------------------------------------------------------------
__global__ void k_update(const float* __restrict__ ema_w, const float* __restrict__ dw,
                         const float* __restrict__ ecs,
                         float* __restrict__ out_emaw, float* __restrict__ out_emb) {
  size_t i = ((size_t)blockIdx.x * blockDim.x + threadIdx.x) * 4;
  int k = (int)(i >> 8);
  float4 w = *(const float4*)(ema_w + i);
  float4 d = *(const float4*)(dw + i);
  float ec = ecs[k];
  float nw0 = w.x * 0.99f + 0.01f * d.x;
  float nw1 = w.y * 0.99f + 0.01f * d.y;
  float nw2 = w.z * 0.99f + 0.01f * d.z;
  float nw3 = w.w * 0.99f + 0.01f * d.w;
  *(float2*)(out_emaw + i) = make_float2(nw0, nw1);
  *(float2*)(out_emaw + i + 2) = make_float2(nw2, nw3);
  *(float2*)(out_emb + i) = make_float2(nw0 / ec, nw1 / ec);
  *(float2*)(out_emb + i + 2) = make_float2(nw2 / ec, nw3 / ec);
}

extern "C" void kernel_launch(void* const* d_in, const int* in_sizes, int n_in,
                              void* d_out, int out_size, void* d_ws, size_t ws_size,
                              hipStream_t stream) {
  const float* inp = (const float*)d_in[0];
  const float* emb = (const float*)d_in[1];
  const float* emacs = (const float*)d_in[2];
  const float* emaw = (const float*)d_in[3];

  float* out = (float*)d_out;
  float* out_loss = out;                                   // [1]
  float* out_quant = out + 1;                              // [N*D]
  float* out_perp = out_quant + (size_t)NROWS * DDIM;      // [1]
  float* out_enc = out_perp + 1;                           // [N*K]
  float* out_emb = out_enc + (size_t)NROWS * KCODES;       // [K*D]
  float* out_ecs = out_emb + (size_t)KCODES * DDIM;        // [K]
  float* out_emaw = out_ecs + KCODES;                      // [K*D]

  // Workspace (~22.3 MB)
  char* p = (char*)d_ws;
  unsigned short* Xb = (unsigned short*)p; p += (size_t)NROWS * DDIM * 2;   // 8 MB
  unsigned short* Ebt = (unsigned short*)p; p += (size_t)KCODES * DDIM * 2; // 4 MB
  float* x2 = (float*)p; p += (size_t)NROWS * 4;
  float* e2 = (float*)p; p += (size_t)KCODES * 4;
  float* candv = (float*)p; p += (size_t)NROWS * 16 * 4;                    // 1 MB
  int* candi = (int*)p; p += (size_t)NROWS * 16 * 4;                        // 1 MB
  float* dw = (float*)p; p += (size_t)KCODES * DDIM * 4;                    // 8 MB
  float* counts = (float*)p; p += (size_t)KCODES * 4;
  float* loss_acc = (float*)p; p += 16;
  int* idxb = (int*)p; p += (size_t)NROWS * 4;

  hipMemsetAsync(dw, 0, ((size_t)KCODES * DDIM + KCODES + 4) * sizeof(float), stream);
  hipMemsetAsync(out_enc, 0, (size_t)NROWS * KCODES * sizeof(float), stream);

  k_prep<<<(NROWS + KCODES) / 4, 256, 0, stream>>>(inp, emb, Xb, Ebt, x2, e2);
  k_dist<<<1024, 256, 0, stream>>>(Xb, Ebt, e2, candv, candi);
  k_select<<<NROWS / 4, 256, 0, stream>>>(inp, emb, x2, e2, candv, candi, idxb);
  k_scatter<<<NROWS / 4, 256, 0, stream>>>(inp, emb, idxb, out_quant, out_enc, counts, dw, loss_acc);
  k_stats<<<1, 256, 0, stream>>>(counts, emacs, loss_acc, out_loss, out_perp, out_ecs);
  k_update<<<(KCODES * DDIM) / 1024, 256, 0, stream>>>(emaw, dw, out_ecs, out_emaw, out_emb);
}

// Round 5
// 955.409 us; speedup vs baseline: 1.8757x; 1.0100x over previous
//
#include <hip/hip_runtime.h>
#include <cstdint>
#include <cstddef>

#define NROWS 16384
#define DDIM  256
#define KCODES 8192
#define MARGIN 1.5f

typedef short bf16x8 __attribute__((ext_vector_type(8)));
typedef float f32x4 __attribute__((ext_vector_type(4)));

__device__ inline unsigned short f2bf(float f) {
  unsigned int u = __float_as_uint(f);
  return (unsigned short)((u + 0x7fffu + ((u >> 16) & 1u)) >> 16);  // RNE
}

// full top-2 insert with (val, index) total order — used only in butterflies
__device__ inline void ins2(float v, int i, float& v1, int& i1, float& v2, int& i2) {
  bool b1 = (v < v1) || (v == v1 && i < i1);
  bool b2 = (v < v2) || (v == v2 && i < i2);
  if (b1) { v2 = v1; i2 = i1; v1 = v; i1 = i; }
  else if (b2) { v2 = v; i2 = i; }
}

// ---------------------------------------------------------------------------
// K0: X rows -> Xb (bf16 row-major) + x2 ; E rows -> Ebt (bf16, MFMA B-frag
// layout: elem(c,k) at ct*4096 + kq*512 + lc*32 + (k&31)) + e2. One wave/row.
// ---------------------------------------------------------------------------
__global__ void k_prep(const float* __restrict__ inp, const float* __restrict__ emb,
                       unsigned short* __restrict__ Xb, unsigned short* __restrict__ Ebt,
                       float* __restrict__ x2, float* __restrict__ e2) {
  int wave = threadIdx.x >> 6, lane = threadIdx.x & 63;
  int row = blockIdx.x * 4 + wave;
  bool isx = row < NROWS;
  const float* src = isx ? (inp + (size_t)row * DDIM) : (emb + (size_t)(row - NROWS) * DDIM);
  float4 v = ((const float4*)src)[lane];
  ushort4 u; u.x = f2bf(v.x); u.y = f2bf(v.y); u.z = f2bf(v.z); u.w = f2bf(v.w);
  if (isx) {
    *(ushort4*)&Xb[(size_t)row * DDIM + lane * 4] = u;
  } else {
    int c = row - NROWS, ct = c >> 4, lc = c & 15;
    size_t off = (size_t)ct * 4096 + (lane >> 3) * 512 + lc * 32 + (lane & 7) * 4;
    *(ushort4*)&Ebt[off] = u;
  }
  float s = v.x * v.x + v.y * v.y + v.z * v.z + v.w * v.w;
#pragma unroll
  for (int o = 32; o >= 1; o >>= 1) s += __shfl_down(s, o, 64);
  if (lane == 0) { if (isx) x2[row] = s; else e2[row - NROWS] = s; }
}

// ---------------------------------------------------------------------------
// K1: barrier-free distance scan, fully scalarized (no loop-carried arrays ->
// no scratch). Wave owns 32 rows (A-frags in named VGPRs) and one 1024-col
// slice; streams B-frags global->reg, 16 MFMA/t, running per-row top-2 of
// d' = e2 - 2*dot (x2 row-constant, argmin-invariant).
// ---------------------------------------------------------------------------
#define DECL_SLOT(s) \
  float v1_##s = 3.4e38f, v2_##s = 3.4e38f; \
  int i1_##s = 0x7fffffff, i2_##s = 0x7fffffff;

#define UPD(s, a) { \
  float d = fmaf(-2.0f, (a), e2c); \
  if (d < v1_##s) { v2_##s = v1_##s; i2_##s = i1_##s; v1_##s = d; i1_##s = col; } \
  else if (d < v2_##s) { v2_##s = d; i2_##s = col; } }

#define RED_SLOT(s, mi, r) { \
  float a1 = v1_##s, a2 = v2_##s; int b1 = i1_##s, b2 = i2_##s; \
  for (int off = 1; off < 16; off <<= 1) { \
    float o1 = __shfl_xor(a1, off, 64); int p1 = __shfl_xor(b1, off, 64); \
    float o2 = __shfl_xor(a2, off, 64); int p2 = __shfl_xor(b2, off, 64); \
    ins2(o1, p1, a1, b1, a2, b2); ins2(o2, p2, a1, b1, a2, b2); } \
  if (lcol == 0) { \
    int row = row0 + (mi) * 16 + quad * 4 + (r); \
    size_t o = ((size_t)row * 8 + slice) * 2; \
    candv[o] = a1; candv[o + 1] = a2; candi[o] = b1; candi[o + 1] = b2; } }

__global__ __launch_bounds__(256, 2) void k_dist(
    const unsigned short* __restrict__ Xb, const unsigned short* __restrict__ Ebt,
    const float* __restrict__ e2,
    float* __restrict__ candv, int* __restrict__ candi) {
  const int lane = threadIdx.x & 63;
  const int w = threadIdx.x >> 6;
  const int lcol = lane & 15, quad = lane >> 4;
  const int row0 = (blockIdx.x >> 3) * 128 + w * 32;
  const int slice = blockIdx.x & 7;

  const unsigned short* ApA = Xb + (size_t)(row0 + lcol) * DDIM + quad * 8;
  const unsigned short* ApB = ApA + 16 * DDIM;
#define DECL_A(q) \
  bf16x8 A0_##q = *(const bf16x8*)(ApA + (q) * 32); \
  bf16x8 A1_##q = *(const bf16x8*)(ApB + (q) * 32);
  DECL_A(0) DECL_A(1) DECL_A(2) DECL_A(3) DECL_A(4) DECL_A(5) DECL_A(6) DECL_A(7)

  DECL_SLOT(0) DECL_SLOT(1) DECL_SLOT(2) DECL_SLOT(3)
  DECL_SLOT(4) DECL_SLOT(5) DECL_SLOT(6) DECL_SLOT(7)

  const unsigned short* Bbase = Ebt + (size_t)slice * 64 * 4096 + lcol * 32 + quad * 8;
  const float* e2p = e2 + slice * 1024 + lcol;
  const int colbase = slice * 1024 + lcol;

#pragma unroll 2
  for (int t = 0; t < 64; ++t) {
    const unsigned short* Bt = Bbase + (size_t)t * 4096;
    bf16x8 B0 = *(const bf16x8*)(Bt);
    bf16x8 B1 = *(const bf16x8*)(Bt + 512);
    bf16x8 B2 = *(const bf16x8*)(Bt + 1024);
    bf16x8 B3 = *(const bf16x8*)(Bt + 1536);
    bf16x8 B4 = *(const bf16x8*)(Bt + 2048);
    bf16x8 B5 = *(const bf16x8*)(Bt + 2560);
    bf16x8 B6 = *(const bf16x8*)(Bt + 3072);
    bf16x8 B7 = *(const bf16x8*)(Bt + 3584);
    float e2c = e2p[t * 16];
    f32x4 acc0 = {0.f, 0.f, 0.f, 0.f};
    f32x4 acc1 = {0.f, 0.f, 0.f, 0.f};
#define MM(q) \
    acc0 = __builtin_amdgcn_mfma_f32_16x16x32_bf16(A0_##q, B##q, acc0, 0, 0, 0); \
    acc1 = __builtin_amdgcn_mfma_f32_16x16x32_bf16(A1_##q, B##q, acc1, 0, 0, 0);
    MM(0) MM(1) MM(2) MM(3) MM(4) MM(5) MM(6) MM(7)
#undef MM
    const int col = colbase + t * 16;
    UPD(0, acc0[0]) UPD(1, acc0[1]) UPD(2, acc0[2]) UPD(3, acc0[3])
    UPD(4, acc1[0]) UPD(5, acc1[1]) UPD(6, acc1[2]) UPD(7, acc1[3])
  }

  // C/D layout: row = quad*4 + reg, col = lane&15
  RED_SLOT(0, 0, 0) RED_SLOT(1, 0, 1) RED_SLOT(2, 0, 2) RED_SLOT(3, 0, 3)
  RED_SLOT(4, 1, 0) RED_SLOT(5, 1, 1) RED_SLOT(6, 1, 2) RED_SLOT(7, 1, 3)
}

// ---------------------------------------------------------------------------
// K2: per row: approx min over 16 candidates; exact fp32 rescore of all
// candidates within min + MARGIN; first-index tiebreak. One wave per row.
// ---------------------------------------------------------------------------
__global__ void k_select(const float* __restrict__ inp, const float* __restrict__ emb,
                         const float* __restrict__ x2, const float* __restrict__ e2,
                         const float* __restrict__ candv, const int* __restrict__ candi,
                         int* __restrict__ idxb) {
  int w = threadIdx.x >> 6, lane = threadIdx.x & 63;
  int row = blockIdx.x * 4 + w;
  float cv = 3.4e38f;
  int ci = 0x7fffffff;
  if (lane < 16) { cv = candv[(size_t)row * 16 + lane]; ci = candi[(size_t)row * 16 + lane]; }
  float m = cv;
#pragma unroll
  for (int o = 32; o >= 1; o >>= 1) m = fminf(m, __shfl_xor(m, o, 64));
  float thr = m + MARGIN;
  unsigned long long b = __ballot(cv <= thr);
  float4 x4 = *(const float4*)(inp + (size_t)row * DDIM + lane * 4);
  float x2r = x2[row];
  float bestv = 3.4e38f;
  int besti = 0x7fffffff;
  while (b) {
    int src = __ffsll(b) - 1; b &= b - 1;
    int j = __shfl(ci, src, 64);
    float4 e4 = *(const float4*)(emb + (size_t)j * DDIM + lane * 4);
    float p = x4.x * e4.x + x4.y * e4.y + x4.z * e4.z + x4.w * e4.w;
#pragma unroll
    for (int o = 32; o >= 1; o >>= 1) p += __shfl_xor(p, o, 64);
    float d2 = (x2r + e2[j]) - 2.0f * p;  // mirror reference formula
    if (d2 < bestv || (d2 == bestv && j < besti)) { bestv = d2; besti = j; }
  }
  if (lane == 0) idxb[row] = besti;
}

// ---------------------------------------------------------------------------
// K2b: encodings one-hot writer. One block per row; 256 threads x 16 float2
// coalesced stores (out_enc is only 8B-aligned). Writes zeros + the single
// 1.0f inline — replaces the 512 MB rocclr fill (4x write-amplified) +
// scatter store.
// ---------------------------------------------------------------------------
__global__ __launch_bounds__(256) void k_enc(const int* __restrict__ idxb,
                                             float* __restrict__ out_enc) {
  const int row = blockIdx.x;
  const int tid = threadIdx.x;
  const int j = idxb[row];
  const int jf2 = j >> 1;
  float* base = out_enc + (size_t)row * KCODES;
  const float2 hot = (j & 1) ? make_float2(0.0f, 1.0f) : make_float2(1.0f, 0.0f);
#pragma unroll
  for (int i = 0; i < 16; ++i) {
    int f2i = i * 256 + tid;
    float2 v = (f2i == jf2) ? hot : make_float2(0.0f, 0.0f);
    *(float2*)(base + f2i * 2) = v;
  }
}

// ---------------------------------------------------------------------------
// K3: per-row scatter: quantized, counts/dw atomics, loss partial.
// ---------------------------------------------------------------------------
__global__ void k_scatter(const float* __restrict__ inp, const float* __restrict__ emb,
                          const int* __restrict__ idxb,
                          float* __restrict__ out_quant,
                          float* __restrict__ counts, float* __restrict__ dw,
                          float* __restrict__ loss_acc) {
  __shared__ float wsum[4];
  int wave = threadIdx.x >> 6, lane = threadIdx.x & 63;
  int row = blockIdx.x * 4 + wave;
  int j = idxb[row];
  float4 x = *(const float4*)(inp + (size_t)row * DDIM + lane * 4);
  float4 e = *(const float4*)(emb + (size_t)j * DDIM + lane * 4);
  size_t qo = (size_t)row * DDIM + lane * 4;  // out_quant only 4B aligned
  out_quant[qo + 0] = x.x + (e.x - x.x);
  out_quant[qo + 1] = x.y + (e.y - x.y);
  out_quant[qo + 2] = x.z + (e.z - x.z);
  out_quant[qo + 3] = x.w + (e.w - x.w);
  size_t dwo = (size_t)j * DDIM + lane * 4;
  atomicAdd(&dw[dwo + 0], x.x);
  atomicAdd(&dw[dwo + 1], x.y);
  atomicAdd(&dw[dwo + 2], x.z);
  atomicAdd(&dw[dwo + 3], x.w);
  float d0 = e.x - x.x, d1 = e.y - x.y, d2 = e.z - x.z, d3 = e.w - x.w;
  float s = d0 * d0 + d1 * d1 + d2 * d2 + d3 * d3;
#pragma unroll
  for (int o = 32; o >= 1; o >>= 1) s += __shfl_down(s, o, 64);
  if (lane == 0) {
    atomicAdd(&counts[j], 1.0f);
    wsum[wave] = s;
  }
  __syncthreads();
  if (threadIdx.x == 0) atomicAdd(loss_acc, wsum[0] + wsum[1] + wsum[2] + wsum[3]);
}

// ---------------------------------------------------------------------------
// K4: single block: n, normalized ecs, perplexity, loss.
// ---------------------------------------------------------------------------
__global__ void k_stats(const float* __restrict__ counts, const float* __restrict__ ema_cs,
                        const float* __restrict__ loss_acc,
                        float* __restrict__ out_loss, float* __restrict__ out_perp,
                        float* __restrict__ out_ecs) {
  __shared__ float red[8];
  int tid = threadIdx.x;
  float ln = 0.0f, lp = 0.0f;
  for (int k = tid; k < KCODES; k += 256) {
    float c = counts[k];
    float er = ema_cs[k] * 0.99f + 0.01f * c;
    ln += er;
    float p = c * (1.0f / 16384.0f);
    lp += p * logf(p + 1e-10f);
  }
  int lane = tid & 63, wave = tid >> 6;
#pragma unroll
  for (int o = 32; o >= 1; o >>= 1) {
    ln += __shfl_down(ln, o, 64);
    lp += __shfl_down(lp, o, 64);
  }
  if (lane == 0) { red[wave] = ln; red[wave + 4] = lp; }
  __syncthreads();
  float n = red[0] + red[1] + red[2] + red[3];
  float plsum = red[4] + red[5] + red[6] + red[7];
  float denom = n + 0.08192f;  // n + K*EPSILON
  for (int k = tid; k < KCODES; k += 256) {
    float c = counts[k];
    float er = ema_cs[k] * 0.99f + 0.01f * c;
    out_ecs[k] = (er + 1e-5f) / denom * n;  // mirror reference op order
  }
  if (tid == 0) {
    out_loss[0] = 0.25f * (loss_acc[0] / 4194304.0f);  // /(N*D)
    out_perp[0] = expf(-plsum);
  }
}

// ---------------------------------------------------------------------------
// K5: EMA update + new embedding (float2: outputs 8B-aligned).
// ---------------------------------------------------------------------------
__global__ void k_update(const float* __restrict__ ema_w, const float* __restrict__ dw,
                         const float* __restrict__ ecs,
                         float* __restrict__ out_emaw, float* __restrict__ out_emb) {
  size_t i = ((size_t)blockIdx.x * blockDim.x + threadIdx.x) * 4;
  int k = (int)(i >> 8);
  float4 w = *(const float4*)(ema_w + i);
  float4 d = *(const float4*)(dw + i);
  float ec = ecs[k];
  float nw0 = w.x * 0.99f + 0.01f * d.x;
  float nw1 = w.y * 0.99f + 0.01f * d.y;
  float nw2 = w.z * 0.99f + 0.01f * d.z;
  float nw3 = w.w * 0.99f + 0.01f * d.w;
  *(float2*)(out_emaw + i) = make_float2(nw0, nw1);
  *(float2*)(out_emaw + i + 2) = make_float2(nw2, nw3);
  *(float2*)(out_emb + i) = make_float2(nw0 / ec, nw1 / ec);
  *(float2*)(out_emb + i + 2) = make_float2(nw2 / ec, nw3 / ec);
}

extern "C" void kernel_launch(void* const* d_in, const int* in_sizes, int n_in,
                              void* d_out, int out_size, void* d_ws, size_t ws_size,
                              hipStream_t stream) {
  const float* inp = (const float*)d_in[0];
  const float* emb = (const float*)d_in[1];
  const float* emacs = (const float*)d_in[2];
  const float* emaw = (const float*)d_in[3];

  float* out = (float*)d_out;
  float* out_loss = out;                                   // [1]
  float* out_quant = out + 1;                              // [N*D]
  float* out_perp = out_quant + (size_t)NROWS * DDIM;      // [1]
  float* out_enc = out_perp + 1;                           // [N*K]
  float* out_emb = out_enc + (size_t)NROWS * KCODES;       // [K*D]
  float* out_ecs = out_emb + (size_t)KCODES * DDIM;        // [K]
  float* out_emaw = out_ecs + KCODES;                      // [K*D]

  // Workspace (~22.3 MB)
  char* p = (char*)d_ws;
  unsigned short* Xb = (unsigned short*)p; p += (size_t)NROWS * DDIM * 2;   // 8 MB
  unsigned short* Ebt = (unsigned short*)p; p += (size_t)KCODES * DDIM * 2; // 4 MB
  float* x2 = (float*)p; p += (size_t)NROWS * 4;
  float* e2 = (float*)p; p += (size_t)KCODES * 4;
  float* candv = (float*)p; p += (size_t)NROWS * 16 * 4;                    // 1 MB
  int* candi = (int*)p; p += (size_t)NROWS * 16 * 4;                        // 1 MB
  float* dw = (float*)p; p += (size_t)KCODES * DDIM * 4;                    // 8 MB
  float* counts = (float*)p; p += (size_t)KCODES * 4;
  float* loss_acc = (float*)p; p += 16;
  int* idxb = (int*)p; p += (size_t)NROWS * 4;

  hipMemsetAsync(dw, 0, ((size_t)KCODES * DDIM + KCODES + 4) * sizeof(float), stream);

  k_prep<<<(NROWS + KCODES) / 4, 256, 0, stream>>>(inp, emb, Xb, Ebt, x2, e2);
  k_dist<<<1024, 256, 0, stream>>>(Xb, Ebt, e2, candv, candi);
  k_select<<<NROWS / 4, 256, 0, stream>>>(inp, emb, x2, e2, candv, candi, idxb);
  k_enc<<<NROWS, 256, 0, stream>>>(idxb, out_enc);
  k_scatter<<<NROWS / 4, 256, 0, stream>>>(inp, emb, idxb, out_quant, counts, dw, loss_acc);
  k_stats<<<1, 256, 0, stream>>>(counts, emacs, loss_acc, out_loss, out_perp, out_ecs);
  k_update<<<(KCODES * DDIM) / 1024, 256, 0, stream>>>(emaw, dw, out_ecs, out_emaw, out_emb);
}